// Round 1
// baseline (196.981 us; speedup 1.0000x reference)
//
#include <hip/hip_runtime.h>
#include <hip/hip_bf16.h>

typedef short s8v __attribute__((ext_vector_type(8)));   // 8 bf16 in 4 VGPRs
typedef float f4v __attribute__((ext_vector_type(4)));   // MFMA accumulator

#define MFMA16(a,b,c) __builtin_amdgcn_mfma_f32_16x16x32_bf16((a),(b),(c),0,0,0)

__device__ __forceinline__ short f2bf(float f) {
    __hip_bfloat16 h = __float2bfloat16(f);
    short s; __builtin_memcpy(&s, &h, 2); return s;
}

// ---------------------------------------------------------------------------
// Kernel 0: repack wq/wk/wv [1024,64] fp32 -> bf16 B-fragment layout.
// Frag id = ((t*32)+ks)*64 + lane, t = m3*4+nt. Lane holds
// B[k = ks*32 + (lane>>4)*8 + j][col = nt*16 + (lane&15)], j=0..7.
// Scale 1/32 (C^-0.5) baked into wq.
// ---------------------------------------------------------------------------
__global__ __launch_bounds__(256) void pack_w_kernel(
    const float* __restrict__ wq, const float* __restrict__ wk,
    const float* __restrict__ wv, short* __restrict__ wpack)
{
    int fid  = blockIdx.x * 256 + threadIdx.x;   // 0..24575
    int lane = fid & 63;
    int ks   = (fid >> 6) & 31;
    int t    = fid >> 11;                        // 0..11
    int m3 = t >> 2, nt = t & 3;
    int col = nt * 16 + (lane & 15);
    int k0  = ks * 32 + (lane >> 4) * 8;
    const float* w = (m3 == 0) ? wq : (m3 == 1 ? wk : wv);
    float sc = (m3 == 0) ? 0.03125f : 1.0f;
    s8v frag;
#pragma unroll
    for (int j = 0; j < 8; j++) frag[j] = f2bf(w[(k0 + j) * 64 + col] * sc);
    ((s8v*)wpack)[fid] = frag;
}

// ---------------------------------------------------------------------------
// Kernel 1: QKV projection. 256 blocks x 256 thr (4 waves).
// Wave handles 16 rows x 192 cols (12 16x16 acc tiles), K-loop 32 steps of 32.
// ---------------------------------------------------------------------------
__global__ __launch_bounds__(256) void qkv_kernel(
    const float* __restrict__ x, const short* __restrict__ wpack,
    const float* __restrict__ bq, const float* __restrict__ bk,
    const float* __restrict__ bv,
    short* __restrict__ qws, short* __restrict__ kws, short* __restrict__ vws)
{
    int tid  = threadIdx.x;
    int wave = tid >> 6, lane = tid & 63;
    int quad = lane >> 4, l16 = lane & 15;
    int rowA = blockIdx.x * 64 + wave * 16 + l16;     // A-frag row (m = lane&15)
    const s8v* wp = (const s8v*)wpack;

    f4v acc[12];
    f4v z = {0.f, 0.f, 0.f, 0.f};
#pragma unroll
    for (int t = 0; t < 12; t++) acc[t] = z;

    for (int ks = 0; ks < 32; ks++) {
        const float4* xp = (const float4*)(x + rowA * 1024 + ks * 32 + quad * 8);
        float4 a0 = xp[0], a1 = xp[1];
        s8v af;
        af[0] = f2bf(a0.x); af[1] = f2bf(a0.y); af[2] = f2bf(a0.z); af[3] = f2bf(a0.w);
        af[4] = f2bf(a1.x); af[5] = f2bf(a1.y); af[6] = f2bf(a1.z); af[7] = f2bf(a1.w);
#pragma unroll
        for (int t = 0; t < 12; t++) {
            s8v bf = wp[(t * 32 + ks) * 64 + lane];   // coalesced 1KB/wave
            acc[t] = MFMA16(af, bf, acc[t]);
        }
    }

    int rowD = blockIdx.x * 64 + wave * 16 + quad * 4; // C/D rows = quad*4+reg
#pragma unroll
    for (int t = 0; t < 12; t++) {
        int m3 = t >> 2, nt = t & 3;
        int col = nt * 16 + l16;                       // C/D col = lane&15
        const float* bp = (m3 == 0) ? bq : ((m3 == 1) ? bk : bv);
        float bias = bp[col] * ((m3 == 0) ? 0.03125f : 1.0f);
        short* dst = (m3 == 0) ? qws : ((m3 == 1) ? kws : vws);
#pragma unroll
        for (int r = 0; r < 4; r++)
            dst[(rowD + r) * 64 + col] = f2bf(acc[t][r] + bias);
    }
}

// ---------------------------------------------------------------------------
// Kernel 2: flash attention. grid(32 qtiles, 8 batches), 256 thr (4 waves).
// Wave owns 16 q-rows; loop over causal j-tiles of 64 keys.
// LDS stride 72 bf16 (16B-aligned, breaks power-of-2 bank aliasing).
// ---------------------------------------------------------------------------
#define LSTR 72
__global__ __launch_bounds__(256) void attn_kernel(
    const short* __restrict__ qws, const short* __restrict__ kws,
    const short* __restrict__ vws, float* __restrict__ out)
{
    __shared__ short Klds[64 * LSTR];        // K[key][dim]
    __shared__ short Vlds[64 * LSTR];        // V^T[dim][key]
    __shared__ short Plds[4 * 16 * LSTR];    // per-wave P[m][key]

    int qt = blockIdx.x, b = blockIdx.y;
    int tid  = threadIdx.x;
    int wave = tid >> 6, lane = tid & 63;
    int quad = lane >> 4, l16 = lane & 15;
    int q0 = qt * 64;

    const short* qb = qws + b * 2048 * 64;
    const short* kb = kws + b * 2048 * 64;
    const short* vb = vws + b * 2048 * 64;

    // Q A-frags for the wave's 16 rows: row m = lane&15, k = st*32 + quad*8 + j
    int qrowA = q0 + wave * 16 + l16;
    s8v qf0 = *(const s8v*)(qb + qrowA * 64 + quad * 8);
    s8v qf1 = *(const s8v*)(qb + qrowA * 64 + 32 + quad * 8);

    f4v o[4];
    f4v z = {0.f, 0.f, 0.f, 0.f};
#pragma unroll
    for (int nt = 0; nt < 4; nt++) o[nt] = z;
    float mrow[4], lrow[4];
#pragma unroll
    for (int r = 0; r < 4; r++) { mrow[r] = -1e30f; lrow[r] = 0.f; }

    for (int jt = 0; jt <= qt; jt++) {
        __syncthreads();   // previous iter's LDS reads done before overwrite
        // ---- stage K tile + transposed V tile ----
        {
            int base = jt * 64;
#pragma unroll
            for (int rep = 0; rep < 2; rep++) {
                int idx = rep * 2048 + tid * 8;
                int key = idx >> 6, d = idx & 63;
                *(s8v*)(Klds + key * LSTR + d) = *(const s8v*)(kb + (base + key) * 64 + d);
                s8v vv = *(const s8v*)(vb + (base + key) * 64 + d);
#pragma unroll
                for (int j = 0; j < 8; j++) Vlds[(d + j) * LSTR + key] = vv[j];
            }
        }
        __syncthreads();

        // ---- S = Q K^T : 4 key-tiles x 2 k-steps ----
        f4v s[4];
#pragma unroll
        for (int nt = 0; nt < 4; nt++) s[nt] = z;
#pragma unroll
        for (int nt = 0; nt < 4; nt++) {
            s8v kf0 = *(const s8v*)(Klds + (nt * 16 + l16) * LSTR + quad * 8);
            s8v kf1 = *(const s8v*)(Klds + (nt * 16 + l16) * LSTR + 32 + quad * 8);
            s[nt] = MFMA16(qf0, kf0, s[nt]);
            s[nt] = MFMA16(qf1, kf1, s[nt]);
        }

        // ---- causal mask on diagonal tile ----
        if (jt == qt) {
            int rowbase = q0 + wave * 16 + quad * 4;
#pragma unroll
            for (int nt = 0; nt < 4; nt++) {
                int key = jt * 64 + nt * 16 + l16;
#pragma unroll
                for (int r = 0; r < 4; r++)
                    if (key > rowbase + r) s[nt][r] = -1e30f;
            }
        }

        // ---- online softmax (rows = quad*4+r, spread over 16 lanes/quad) ----
        float mnew[4], alpha[4];
#pragma unroll
        for (int r = 0; r < 4; r++) {
            float mx = fmaxf(fmaxf(s[0][r], s[1][r]), fmaxf(s[2][r], s[3][r]));
#pragma unroll
            for (int off = 1; off < 16; off <<= 1) mx = fmaxf(mx, __shfl_xor(mx, off, 64));
            mnew[r] = fmaxf(mrow[r], mx);
            alpha[r] = __expf(mrow[r] - mnew[r]);
            mrow[r] = mnew[r];
        }
#pragma unroll
        for (int r = 0; r < 4; r++) {
            float rs = 0.f;
#pragma unroll
            for (int nt = 0; nt < 4; nt++) {
                float p = __expf(s[nt][r] - mnew[r]);
                s[nt][r] = p;
                rs += p;
            }
#pragma unroll
            for (int off = 1; off < 16; off <<= 1) rs += __shfl_xor(rs, off, 64);
            lrow[r] = lrow[r] * alpha[r] + rs;
            o[0][r] *= alpha[r]; o[1][r] *= alpha[r];
            o[2][r] *= alpha[r]; o[3][r] *= alpha[r];
        }

        // ---- P (C-layout) -> LDS -> A-layout ----
        short* pw = Plds + wave * 16 * LSTR;
#pragma unroll
        for (int nt = 0; nt < 4; nt++)
#pragma unroll
            for (int r = 0; r < 4; r++)
                pw[(quad * 4 + r) * LSTR + nt * 16 + l16] = f2bf(s[nt][r]);
        __syncthreads();

        // ---- O += P V ----
#pragma unroll
        for (int st = 0; st < 2; st++) {
            s8v pf = *(const s8v*)(pw + l16 * LSTR + st * 32 + quad * 8);
#pragma unroll
            for (int nt = 0; nt < 4; nt++) {
                s8v vf = *(const s8v*)(Vlds + (nt * 16 + l16) * LSTR + st * 32 + quad * 8);
                o[nt] = MFMA16(pf, vf, o[nt]);
            }
        }
    }

    // ---- epilogue: normalize + fp32 store ----
    int orow = q0 + wave * 16 + quad * 4;
    float* ob = out + b * 2048 * 64;
#pragma unroll
    for (int nt = 0; nt < 4; nt++) {
        int col = nt * 16 + l16;
#pragma unroll
        for (int r = 0; r < 4; r++)
            ob[(orow + r) * 64 + col] = o[nt][r] / lrow[r];
    }
}

// ---------------------------------------------------------------------------
extern "C" void kernel_launch(void* const* d_in, const int* in_sizes, int n_in,
                              void* d_out, int out_size, void* d_ws, size_t ws_size,
                              hipStream_t stream) {
    const float* x  = (const float*)d_in[0];
    const float* wq = (const float*)d_in[1];
    const float* bq = (const float*)d_in[2];
    const float* wk = (const float*)d_in[3];
    const float* bk = (const float*)d_in[4];
    const float* wv = (const float*)d_in[5];
    const float* bv = (const float*)d_in[6];
    float* out = (float*)d_out;

    char* ws = (char*)d_ws;
    short* wpack = (short*)ws;                      // 384 KiB
    short* qws   = (short*)(ws + (1 << 19));        // 2 MiB each
    short* kws   = qws + 8 * 2048 * 64;
    short* vws   = kws + 8 * 2048 * 64;

    hipLaunchKernelGGL(pack_w_kernel, dim3(96),     dim3(256), 0, stream, wq, wk, wv, wpack);
    hipLaunchKernelGGL(qkv_kernel,    dim3(256),    dim3(256), 0, stream,
                       x, wpack, bq, bk, bv, qws, kws, vws);
    hipLaunchKernelGGL(attn_kernel,   dim3(32, 8),  dim3(256), 0, stream, qws, kws, vws, out);
}